// Round 9
// baseline (212.499 us; speedup 1.0000x reference)
//
#include <hip/hip_runtime.h>
#include <hip/hip_bf16.h>

// Problem constants (B,H,W,C = 32,32,32,256 -> l = 1024)
#define BATCH 32
#define L 1024
#define CD 256
#define TM 64          // pred rows per block
#define TN 64          // query cols per n-tile
#define NTB 8          // n-tiles per block (nt-split: 2 blocks per (b,rt))
#define KC 128         // K half-phase staged per barrier pair
#define RT_PER_B 16
#define SQ_LD (KC + 8) // sQ leading dim (bf16): 272-B row stride (17*16 B)

typedef __bf16 bf16x8 __attribute__((ext_vector_type(8)));
typedef float  f32x4  __attribute__((ext_vector_type(4)));

__device__ __forceinline__ unsigned int enc_f32(float f) {
    unsigned int u = __float_as_uint(f);
    return ((int)u < 0) ? ~u : (u | 0x80000000u);
}
__device__ __forceinline__ float dec_f32(unsigned int u) {
    u = (u & 0x80000000u) ? (u & 0x7FFFFFFFu) : ~u;
    return __uint_as_float(u);
}
__device__ __forceinline__ unsigned long long pmax(unsigned long long a, unsigned long long b) {
    return a > b ? a : b;
}
__device__ __forceinline__ bf16x8 cvt8(float4 v0, float4 v1) {
    bf16x8 o;
    o[0] = (__bf16)v0.x; o[1] = (__bf16)v0.y; o[2] = (__bf16)v0.z; o[3] = (__bf16)v0.w;
    o[4] = (__bf16)v1.x; o[5] = (__bf16)v1.y; o[6] = (__bf16)v1.z; o[7] = (__bf16)v1.w;
    return o;
}

// Kernel 1: block = (batch, 64-row tile, column half). 2x2 waves, each
// 32 rows x 32 cols. A (preds) lives in 16 INDIVIDUALLY NAMED bf16x8 register
// variables (R7/R8 lesson: an af[2][8] array indexed via the kc loop is
// demoted to scratch by SROA before unrolling -> 50 MB spill traffic).
// kc phases are manually unrolled; MFMA steps take A-fragments by name with
// literal kp. B (queries) staged per phase via register-prefetch pipeline
// into a conflict-free lane-major sQ layout.
__global__ __launch_bounds__(256, 3) void mm_argmax_kernel(
    const float* __restrict__ qg,   // feats1 [B][L][CD]  (queries)
    const float* __restrict__ pg,   // feats2 [B][L][CD]  (preds)
    unsigned long long* __restrict__ colpart,  // [B][16][L] packed (enc(val)<<32)|~a
    unsigned long long* __restrict__ rowpart)  // [B][16][2][64] packed (enc<<32)|~j
{
    __shared__ __bf16 sQ[TN][SQ_LD];            // 17408 B
    __shared__ unsigned long long sCol[TN];     // 512 B
    __shared__ unsigned long long sRowW[2][TM]; // 1024 B

    const int tid = threadIdx.x;
    const int bid = blockIdx.x;
    // bid = (rt*2+h)*32 + b: round-robin dispatch -> all of batch b on XCD b%8
    const int b    = bid & 31;
    const int rth  = bid >> 5;
    const int rt   = rth >> 1;
    const int h    = rth & 1;
    const int row0 = rt * TM;
    const int nt0  = h * NTB;

    const int lane = tid & 63;
    const int w    = tid >> 6;
    const int wm   = w >> 1;      // wave row: 32 pred rows
    const int wn   = w & 1;       // wave col: 32 query cols
    const int quad = lane >> 4;
    const int l16  = lane & 15;

    const float* qB = qg + (size_t)b * L * CD;

    // ---- A-fragments in named registers (once; nt-invariant) ----
    // aTM_KP: lane holds A[m = row0 + wm*32 + TM*16 + l16][k = KP*32 + quad*8 .. +8]
    const float* pA = pg + ((size_t)b * L + row0 + wm * 32 + l16) * CD + quad * 8;
    bf16x8 a00, a01, a02, a03, a04, a05, a06, a07;
    bf16x8 a10, a11, a12, a13, a14, a15, a16, a17;
#define LOADA(V, TMv, KPv)                                                     \
    {                                                                          \
        float4 v0 = *(const float4*)(pA + (TMv) * 16 * CD + (KPv) * 32);       \
        float4 v1 = *(const float4*)(pA + (TMv) * 16 * CD + (KPv) * 32 + 4);   \
        V = cvt8(v0, v1);                                                      \
    }
    LOADA(a00, 0, 0) LOADA(a01, 0, 1) LOADA(a02, 0, 2) LOADA(a03, 0, 3)
    LOADA(a04, 0, 4) LOADA(a05, 0, 5) LOADA(a06, 0, 6) LOADA(a07, 0, 7)
    LOADA(a10, 1, 0) LOADA(a11, 1, 1) LOADA(a12, 1, 2) LOADA(a13, 1, 3)
    LOADA(a14, 1, 4) LOADA(a15, 1, 5) LOADA(a16, 1, 6) LOADA(a17, 1, 7)
#undef LOADA

    // ---- q staging map (conflict-free lane-major) ----
    const int srow = tid >> 4;    // 0..15
    const int schk = tid & 15;    // 0..15

    float4 pf[8];
    auto prefetchQ = [&](int nnt, int nkc) {
        #pragma unroll
        for (int j = 0; j < 4; ++j) {
            const float* src =
                qB + (size_t)(nnt * TN + j * 16 + srow) * CD + nkc * KC + schk * 8;
            pf[2 * j]     = *(const float4*)src;
            pf[2 * j + 1] = *(const float4*)(src + 4);
        }
    };
    auto stageQ = [&]() {
        #pragma unroll
        for (int j = 0; j < 4; ++j)
            *(bf16x8*)&sQ[j * 16 + srow][schk * 8] = cvt8(pf[2 * j], pf[2 * j + 1]);
    };

    prefetchQ(nt0, 0);   // first phase

    unsigned long long rowbest[2][4];
    #pragma unroll
    for (int tm = 0; tm < 2; ++tm)
        #pragma unroll
        for (int r = 0; r < 4; ++r) rowbest[tm][r] = 0ull;
    unsigned long long pend[2] = {0ull, 0ull};

#define MSTEP(KP, A0, A1)                                                          \
    {                                                                              \
        const int kb = ((KP) & 3) * 32 + quad * 8;                                 \
        bf16x8 b0 = *(const bf16x8*)&sQ[wn * 32 +      l16][kb];                   \
        bf16x8 b1 = *(const bf16x8*)&sQ[wn * 32 + 16 + l16][kb];                   \
        acc[0][0] = __builtin_amdgcn_mfma_f32_16x16x32_bf16(A0, b0, acc[0][0], 0, 0, 0); \
        acc[0][1] = __builtin_amdgcn_mfma_f32_16x16x32_bf16(A0, b1, acc[0][1], 0, 0, 0); \
        acc[1][0] = __builtin_amdgcn_mfma_f32_16x16x32_bf16(A1, b0, acc[1][0], 0, 0, 0); \
        acc[1][1] = __builtin_amdgcn_mfma_f32_16x16x32_bf16(A1, b1, acc[1][1], 0, 0, 0); \
    }

    for (int t = 0; t < NTB; ++t) {
        const int nt = nt0 + t;
        f32x4 acc[2][2];
        #pragma unroll
        for (int tm = 0; tm < 2; ++tm)
            #pragma unroll
            for (int tn = 0; tn < 2; ++tn) acc[tm][tn] = (f32x4){0.f, 0.f, 0.f, 0.f};

        // ======== phase kc = 0 (kp 0..3) ========
        if (t) __syncthreads();              // B1: prev-phase readers of sQ done
        // piggyback drain: wm=1 combines+stores tile nt-1's column partials
        if (t > 0 && wm == 1 && quad == 0) {
            #pragma unroll
            for (int tn = 0; tn < 2; ++tn) {
                const int c = wn * 32 + tn * 16 + l16;
                colpart[((size_t)b * RT_PER_B + rt) * L + (nt - 1) * TN + c] =
                    pmax(pend[tn], sCol[c]);
            }
        }
        stageQ();
        prefetchQ(nt, 1);                    // overlaps barrier + compute
        __syncthreads();                     // B2: sQ ready
        MSTEP(0, a00, a10) MSTEP(1, a01, a11) MSTEP(2, a02, a12) MSTEP(3, a03, a13)

        // ======== phase kc = 1 (kp 4..7) ========
        __syncthreads();                     // B1
        stageQ();
        if (t != NTB - 1) prefetchQ(nt + 1, 0);
        __syncthreads();                     // B2
        MSTEP(4, a04, a14) MSTEP(5, a05, a15) MSTEP(6, a06, a16) MSTEP(7, a07, a17)

        // ---- epilogue: column partials (32 rows per wave) + row running max ----
        // C/D layout: col = l16, row = tm*16 + quad*4 + r  (m89/m91 verified)
        #pragma unroll
        for (int tn = 0; tn < 2; ++tn) {
            const unsigned int jcol = (unsigned int)(nt * TN + wn * 32 + tn * 16 + l16);
            const unsigned long long jpk = (unsigned long long)(unsigned int)(~jcol);
            unsigned long long cbest = 0ull;
            #pragma unroll
            for (int tm = 0; tm < 2; ++tm) {
                #pragma unroll
                for (int r = 0; r < 4; ++r) {
                    const unsigned int e = enc_f32(acc[tm][tn][r]);
                    const unsigned int aidx =
                        (unsigned int)(row0 + wm * 32 + tm * 16 + quad * 4 + r);
                    cbest = pmax(cbest, ((unsigned long long)e << 32) | (unsigned int)(~aidx));
                    rowbest[tm][r] = pmax(rowbest[tm][r], ((unsigned long long)e << 32) | jpk);
                }
            }
            cbest = pmax(cbest, __shfl_xor(cbest, 16));
            cbest = pmax(cbest, __shfl_xor(cbest, 32));
            if (quad == 0) {
                const int c = wn * 32 + tn * 16 + l16;
                if (wm == 0) sCol[c] = cbest;
                else         pend[tn] = cbest;
            }
        }
    }
#undef MSTEP

    // ---- final column drain for tile nt0+NTB-1 ----
    __syncthreads();
    if (wm == 1 && quad == 0) {
        #pragma unroll
        for (int tn = 0; tn < 2; ++tn) {
            const int c = wn * 32 + tn * 16 + l16;
            colpart[((size_t)b * RT_PER_B + rt) * L + (nt0 + NTB - 1) * TN + c] =
                pmax(pend[tn], sCol[c]);
        }
    }

    // ---- row partial argmax: reduce over 16 col-lanes, combine wn pair ----
    #pragma unroll
    for (int tm = 0; tm < 2; ++tm) {
        #pragma unroll
        for (int r = 0; r < 4; ++r) {
            unsigned long long pk = rowbest[tm][r];
            pk = pmax(pk, __shfl_xor(pk, 1));
            pk = pmax(pk, __shfl_xor(pk, 2));
            pk = pmax(pk, __shfl_xor(pk, 4));
            pk = pmax(pk, __shfl_xor(pk, 8));
            rowbest[tm][r] = pk;
        }
    }
    if (l16 == 0) {
        #pragma unroll
        for (int tm = 0; tm < 2; ++tm)
            #pragma unroll
            for (int r = 0; r < 4; ++r)
                sRowW[wn][wm * 32 + tm * 16 + quad * 4 + r] = rowbest[tm][r];
    }
    __syncthreads();
    if (w == 0) {
        unsigned long long m = pmax(sRowW[0][lane], sRowW[1][lane]);
        rowpart[(((size_t)b * RT_PER_B + rt) * 2 + h) * TM + lane] = m;
    }
}

// Kernel 2: per-batch final reduction — combine rowpart halves -> max2,
// combine colpart over row-tiles -> max1/sims, mutual-NN check, masked mean.
__global__ __launch_bounds__(256) void finalize_kernel(
    const unsigned long long* __restrict__ colpart,
    const unsigned long long* __restrict__ rowpart,
    float* __restrict__ out)
{
    __shared__ int sMax2[L];
    __shared__ float sSum[4];
    __shared__ int sCnt[4];
    const int b = blockIdx.x;
    const int tid = threadIdx.x;

    for (int i = tid; i < L; i += 256) {
        const int rt = i >> 6, a = i & 63;
        const size_t base = (((size_t)b * RT_PER_B + rt) * 2) * TM + a;
        unsigned long long m = pmax(rowpart[base], rowpart[base + TM]);
        sMax2[i] = (int)(~(unsigned int)m);
    }
    __syncthreads();

    float sum = 0.f;
    int cnt = 0;
    #pragma unroll
    for (int i = 0; i < 4; ++i) {
        const int j = tid + i * 256;
        unsigned long long best = 0ull;
        #pragma unroll
        for (int rt = 0; rt < RT_PER_B; ++rt)
            best = pmax(best, colpart[((size_t)b * RT_PER_B + rt) * L + j]);
        const int a = (int)(~(unsigned int)best) & (L - 1);    // max1[j]
        const float val = dec_f32((unsigned int)(best >> 32)); // sims[j]
        if (sMax2[a] == j) { sum += val; ++cnt; }              // mutual NN
    }
    #pragma unroll
    for (int o = 32; o >= 1; o >>= 1) {
        sum += __shfl_down(sum, o);
        cnt += __shfl_down(cnt, o);
    }
    if ((tid & 63) == 0) { sSum[tid >> 6] = sum; sCnt[tid >> 6] = cnt; }
    __syncthreads();
    if (tid == 0) {
        float S = sSum[0] + sSum[1] + sSum[2] + sSum[3];
        int   C = sCnt[0] + sCnt[1] + sCnt[2] + sCnt[3];
        out[b] = S / fmaxf((float)C, 1.0f);
    }
}

extern "C" void kernel_launch(void* const* d_in, const int* in_sizes, int n_in,
                              void* d_out, int out_size, void* d_ws, size_t ws_size,
                              hipStream_t stream) {
    const float* q = (const float*)d_in[0];   // feats1
    const float* p = (const float*)d_in[1];   // feats2
    float* out = (float*)d_out;

    // ws layout: colpart [32][16][1024] u64 = 4 MiB, then
    //            rowpart [32][16][2][64] u64 = 512 KiB.
    // Every slot written by kernel 1 before kernel 2 reads it -> no init needed.
    unsigned long long* colpart = (unsigned long long*)d_ws;
    unsigned long long* rowpart =
        (unsigned long long*)((char*)d_ws + (size_t)BATCH * RT_PER_B * L * sizeof(unsigned long long));

    mm_argmax_kernel<<<BATCH * RT_PER_B * 2, 256, 0, stream>>>(q, p, colpart, rowpart);
    finalize_kernel<<<BATCH, 256, 0, stream>>>(colpart, rowpart, out);
}

// Round 10
// 144.226 us; speedup vs baseline: 1.4734x; 1.4734x over previous
//
#include <hip/hip_runtime.h>
#include <hip/hip_bf16.h>

// Problem constants (B,H,W,C = 32,32,32,256 -> l = 1024)
#define BATCH 32
#define L 1024
#define CD 256
#define TM 64          // pred rows per block
#define TN 64          // query cols per n-tile
#define NTB 8          // n-tiles per block (nt-split: 2 blocks per (b,rt))
#define KC 128         // K half-phase staged per barrier pair
#define RT_PER_B 16
#define SQ_LD (KC + 8) // sQ leading dim (bf16): 272-B row stride (17*16 B)

typedef __bf16 bf16x8 __attribute__((ext_vector_type(8)));
typedef float  f32x4  __attribute__((ext_vector_type(4)));

__device__ __forceinline__ unsigned int enc_f32(float f) {
    unsigned int u = __float_as_uint(f);
    return ((int)u < 0) ? ~u : (u | 0x80000000u);
}
__device__ __forceinline__ float dec_f32(unsigned int u) {
    u = (u & 0x80000000u) ? (u & 0x7FFFFFFFu) : ~u;
    return __uint_as_float(u);
}
__device__ __forceinline__ unsigned long long pmax(unsigned long long a, unsigned long long b) {
    return a > b ? a : b;
}
__device__ __forceinline__ bf16x8 cvt8(float4 v0, float4 v1) {
    bf16x8 o;
    o[0] = (__bf16)v0.x; o[1] = (__bf16)v0.y; o[2] = (__bf16)v0.z; o[3] = (__bf16)v0.w;
    o[4] = (__bf16)v1.x; o[5] = (__bf16)v1.y; o[6] = (__bf16)v1.z; o[7] = (__bf16)v1.w;
    return o;
}

// Kernel 1: block = (batch, 64-row tile, column half). 2x2 waves, each
// 32 rows x 32 cols. A (preds) lives in 16 individually named bf16x8
// registers. R7/R8/R9 lesson: with __launch_bounds__(256,3) the ~168-VGPR
// cap forces the allocator to spill the af fragments (50 MB scratch
// traffic, VGPR_Count 84). (256,2) raises the cap to 256 so af stays
// resident; at ~150 VGPR the HW still schedules 3 waves/EU.
__global__ __launch_bounds__(256, 2) void mm_argmax_kernel(
    const float* __restrict__ qg,   // feats1 [B][L][CD]  (queries)
    const float* __restrict__ pg,   // feats2 [B][L][CD]  (preds)
    unsigned long long* __restrict__ colpart,  // [B][16][L] packed (enc(val)<<32)|~a
    unsigned long long* __restrict__ rowpart)  // [B][16][2][64] packed (enc<<32)|~j
{
    __shared__ __bf16 sQ[TN][SQ_LD];            // 17408 B
    __shared__ unsigned long long sCol[TN];     // 512 B
    __shared__ unsigned long long sRowW[2][TM]; // 1024 B

    const int tid = threadIdx.x;
    const int bid = blockIdx.x;
    // bid = (rt*2+h)*32 + b: round-robin dispatch -> all of batch b on XCD b%8
    const int b    = bid & 31;
    const int rth  = bid >> 5;
    const int rt   = rth >> 1;
    const int h    = rth & 1;
    const int row0 = rt * TM;
    const int nt0  = h * NTB;

    const int lane = tid & 63;
    const int w    = tid >> 6;
    const int wm   = w >> 1;      // wave row: 32 pred rows
    const int wn   = w & 1;       // wave col: 32 query cols
    const int quad = lane >> 4;
    const int l16  = lane & 15;

    const float* qB = qg + (size_t)b * L * CD;

    // ---- A-fragments in named registers (once; nt-invariant) ----
    // aTM_KP: lane holds A[m = row0 + wm*32 + TM*16 + l16][k = KP*32 + quad*8 .. +8]
    const float* pA = pg + ((size_t)b * L + row0 + wm * 32 + l16) * CD + quad * 8;
    bf16x8 a00, a01, a02, a03, a04, a05, a06, a07;
    bf16x8 a10, a11, a12, a13, a14, a15, a16, a17;
#define LOADA(V, TMv, KPv)                                                     \
    {                                                                          \
        float4 v0 = *(const float4*)(pA + (TMv) * 16 * CD + (KPv) * 32);       \
        float4 v1 = *(const float4*)(pA + (TMv) * 16 * CD + (KPv) * 32 + 4);   \
        V = cvt8(v0, v1);                                                      \
    }
    LOADA(a00, 0, 0) LOADA(a01, 0, 1) LOADA(a02, 0, 2) LOADA(a03, 0, 3)
    LOADA(a04, 0, 4) LOADA(a05, 0, 5) LOADA(a06, 0, 6) LOADA(a07, 0, 7)
    LOADA(a10, 1, 0) LOADA(a11, 1, 1) LOADA(a12, 1, 2) LOADA(a13, 1, 3)
    LOADA(a14, 1, 4) LOADA(a15, 1, 5) LOADA(a16, 1, 6) LOADA(a17, 1, 7)
#undef LOADA

    // ---- q staging map (conflict-free lane-major) ----
    const int srow = tid >> 4;    // 0..15
    const int schk = tid & 15;    // 0..15

    float4 pf[8];
    auto prefetchQ = [&](int nnt, int nkc) {
        #pragma unroll
        for (int j = 0; j < 4; ++j) {
            const float* src =
                qB + (size_t)(nnt * TN + j * 16 + srow) * CD + nkc * KC + schk * 8;
            pf[2 * j]     = *(const float4*)src;
            pf[2 * j + 1] = *(const float4*)(src + 4);
        }
    };
    auto stageQ = [&]() {
        #pragma unroll
        for (int j = 0; j < 4; ++j)
            *(bf16x8*)&sQ[j * 16 + srow][schk * 8] = cvt8(pf[2 * j], pf[2 * j + 1]);
    };

    prefetchQ(nt0, 0);   // first phase

    unsigned long long rowbest[2][4];
    #pragma unroll
    for (int tm = 0; tm < 2; ++tm)
        #pragma unroll
        for (int r = 0; r < 4; ++r) rowbest[tm][r] = 0ull;
    unsigned long long pend[2] = {0ull, 0ull};

#define MSTEP(KP, A0, A1)                                                          \
    {                                                                              \
        const int kb = ((KP) & 3) * 32 + quad * 8;                                 \
        bf16x8 b0 = *(const bf16x8*)&sQ[wn * 32 +      l16][kb];                   \
        bf16x8 b1 = *(const bf16x8*)&sQ[wn * 32 + 16 + l16][kb];                   \
        acc[0][0] = __builtin_amdgcn_mfma_f32_16x16x32_bf16(A0, b0, acc[0][0], 0, 0, 0); \
        acc[0][1] = __builtin_amdgcn_mfma_f32_16x16x32_bf16(A0, b1, acc[0][1], 0, 0, 0); \
        acc[1][0] = __builtin_amdgcn_mfma_f32_16x16x32_bf16(A1, b0, acc[1][0], 0, 0, 0); \
        acc[1][1] = __builtin_amdgcn_mfma_f32_16x16x32_bf16(A1, b1, acc[1][1], 0, 0, 0); \
    }

    for (int t = 0; t < NTB; ++t) {
        const int nt = nt0 + t;
        f32x4 acc[2][2];
        #pragma unroll
        for (int tm = 0; tm < 2; ++tm)
            #pragma unroll
            for (int tn = 0; tn < 2; ++tn) acc[tm][tn] = (f32x4){0.f, 0.f, 0.f, 0.f};

        // ======== phase kc = 0 (kp 0..3) ========
        if (t) __syncthreads();              // B1: prev-phase readers of sQ done
        // piggyback drain: wm=1 combines+stores tile nt-1's column partials
        if (t > 0 && wm == 1 && quad == 0) {
            #pragma unroll
            for (int tn = 0; tn < 2; ++tn) {
                const int c = wn * 32 + tn * 16 + l16;
                colpart[((size_t)b * RT_PER_B + rt) * L + (nt - 1) * TN + c] =
                    pmax(pend[tn], sCol[c]);
            }
        }
        stageQ();
        prefetchQ(nt, 1);                    // overlaps barrier + compute
        __syncthreads();                     // B2: sQ ready
        MSTEP(0, a00, a10) MSTEP(1, a01, a11) MSTEP(2, a02, a12) MSTEP(3, a03, a13)

        // ======== phase kc = 1 (kp 4..7) ========
        __syncthreads();                     // B1
        stageQ();
        if (t != NTB - 1) prefetchQ(nt + 1, 0);
        __syncthreads();                     // B2
        MSTEP(4, a04, a14) MSTEP(5, a05, a15) MSTEP(6, a06, a16) MSTEP(7, a07, a17)

        // ---- epilogue: column partials (32 rows per wave) + row running max ----
        // C/D layout: col = l16, row = tm*16 + quad*4 + r  (m89/m91 verified)
        #pragma unroll
        for (int tn = 0; tn < 2; ++tn) {
            const unsigned int jcol = (unsigned int)(nt * TN + wn * 32 + tn * 16 + l16);
            const unsigned long long jpk = (unsigned long long)(unsigned int)(~jcol);
            unsigned long long cbest = 0ull;
            #pragma unroll
            for (int tm = 0; tm < 2; ++tm) {
                #pragma unroll
                for (int r = 0; r < 4; ++r) {
                    const unsigned int e = enc_f32(acc[tm][tn][r]);
                    const unsigned int aidx =
                        (unsigned int)(row0 + wm * 32 + tm * 16 + quad * 4 + r);
                    cbest = pmax(cbest, ((unsigned long long)e << 32) | (unsigned int)(~aidx));
                    rowbest[tm][r] = pmax(rowbest[tm][r], ((unsigned long long)e << 32) | jpk);
                }
            }
            cbest = pmax(cbest, __shfl_xor(cbest, 16));
            cbest = pmax(cbest, __shfl_xor(cbest, 32));
            if (quad == 0) {
                const int c = wn * 32 + tn * 16 + l16;
                if (wm == 0) sCol[c] = cbest;
                else         pend[tn] = cbest;
            }
        }
    }
#undef MSTEP

    // ---- final column drain for tile nt0+NTB-1 ----
    __syncthreads();
    if (wm == 1 && quad == 0) {
        #pragma unroll
        for (int tn = 0; tn < 2; ++tn) {
            const int c = wn * 32 + tn * 16 + l16;
            colpart[((size_t)b * RT_PER_B + rt) * L + (nt0 + NTB - 1) * TN + c] =
                pmax(pend[tn], sCol[c]);
        }
    }

    // ---- row partial argmax: reduce over 16 col-lanes, combine wn pair ----
    #pragma unroll
    for (int tm = 0; tm < 2; ++tm) {
        #pragma unroll
        for (int r = 0; r < 4; ++r) {
            unsigned long long pk = rowbest[tm][r];
            pk = pmax(pk, __shfl_xor(pk, 1));
            pk = pmax(pk, __shfl_xor(pk, 2));
            pk = pmax(pk, __shfl_xor(pk, 4));
            pk = pmax(pk, __shfl_xor(pk, 8));
            rowbest[tm][r] = pk;
        }
    }
    if (l16 == 0) {
        #pragma unroll
        for (int tm = 0; tm < 2; ++tm)
            #pragma unroll
            for (int r = 0; r < 4; ++r)
                sRowW[wn][wm * 32 + tm * 16 + quad * 4 + r] = rowbest[tm][r];
    }
    __syncthreads();
    if (w == 0) {
        unsigned long long m = pmax(sRowW[0][lane], sRowW[1][lane]);
        rowpart[(((size_t)b * RT_PER_B + rt) * 2 + h) * TM + lane] = m;
    }
}

// Kernel 2: per-batch final reduction — combine rowpart halves -> max2,
// combine colpart over row-tiles -> max1/sims, mutual-NN check, masked mean.
__global__ __launch_bounds__(256) void finalize_kernel(
    const unsigned long long* __restrict__ colpart,
    const unsigned long long* __restrict__ rowpart,
    float* __restrict__ out)
{
    __shared__ int sMax2[L];
    __shared__ float sSum[4];
    __shared__ int sCnt[4];
    const int b = blockIdx.x;
    const int tid = threadIdx.x;

    for (int i = tid; i < L; i += 256) {
        const int rt = i >> 6, a = i & 63;
        const size_t base = (((size_t)b * RT_PER_B + rt) * 2) * TM + a;
        unsigned long long m = pmax(rowpart[base], rowpart[base + TM]);
        sMax2[i] = (int)(~(unsigned int)m);
    }
    __syncthreads();

    float sum = 0.f;
    int cnt = 0;
    #pragma unroll
    for (int i = 0; i < 4; ++i) {
        const int j = tid + i * 256;
        unsigned long long best = 0ull;
        #pragma unroll
        for (int rt = 0; rt < RT_PER_B; ++rt)
            best = pmax(best, colpart[((size_t)b * RT_PER_B + rt) * L + j]);
        const int a = (int)(~(unsigned int)best) & (L - 1);    // max1[j]
        const float val = dec_f32((unsigned int)(best >> 32)); // sims[j]
        if (sMax2[a] == j) { sum += val; ++cnt; }              // mutual NN
    }
    #pragma unroll
    for (int o = 32; o >= 1; o >>= 1) {
        sum += __shfl_down(sum, o);
        cnt += __shfl_down(cnt, o);
    }
    if ((tid & 63) == 0) { sSum[tid >> 6] = sum; sCnt[tid >> 6] = cnt; }
    __syncthreads();
    if (tid == 0) {
        float S = sSum[0] + sSum[1] + sSum[2] + sSum[3];
        int   C = sCnt[0] + sCnt[1] + sCnt[2] + sCnt[3];
        out[b] = S / fmaxf((float)C, 1.0f);
    }
}

extern "C" void kernel_launch(void* const* d_in, const int* in_sizes, int n_in,
                              void* d_out, int out_size, void* d_ws, size_t ws_size,
                              hipStream_t stream) {
    const float* q = (const float*)d_in[0];   // feats1
    const float* p = (const float*)d_in[1];   // feats2
    float* out = (float*)d_out;

    // ws layout: colpart [32][16][1024] u64 = 4 MiB, then
    //            rowpart [32][16][2][64] u64 = 512 KiB.
    // Every slot written by kernel 1 before kernel 2 reads it -> no init needed.
    unsigned long long* colpart = (unsigned long long*)d_ws;
    unsigned long long* rowpart =
        (unsigned long long*)((char*)d_ws + (size_t)BATCH * RT_PER_B * L * sizeof(unsigned long long));

    mm_argmax_kernel<<<BATCH * RT_PER_B * 2, 256, 0, stream>>>(q, p, colpart, rowpart);
    finalize_kernel<<<BATCH, 256, 0, stream>>>(colpart, rowpart, out);
}